// Round 4
// baseline (2911.260 us; speedup 1.0000x reference)
//
#include <hip/hip_runtime.h>
#include <hip/hip_fp16.h>
#include <hip/hip_bf16.h>

// ---------------------------------------------------------------------------
// HAConvGNN forward. Round 4: all GRU recurrences rebuilt as per-block MFMA
// GEMM recurrences (weights register-resident as bf16 fragments); remaining
// fp32 GEMMs (scores/PV/xg1/xg2/dense) moved to the MFMA kernel.
// ---------------------------------------------------------------------------

typedef __attribute__((ext_vector_type(8))) short  bf16x8;
typedef __attribute__((ext_vector_type(4))) float  f32x4;

__device__ inline unsigned short f2bs(float f) {
  __hip_bfloat16 h = __float2bfloat16(f);
  unsigned short u; __builtin_memcpy(&u, &h, 2); return u;
}

__device__ inline float sigf(float x) { return 1.f / (1.f + __expf(-x)); }
__device__ inline float tanhf_(float x) {
  const float e = __expf(-2.f * fabsf(x));
  return copysignf((1.f - e) / (1.f + e), x);
}

// ---------------- bf16 MFMA GEMM -------------------------------------------
// C[M,N] = A[M,K] * B^T (B stored [N][K]) with batching z=(batch, ksplit).
// ABF/BBF: operand is bf16 in global (else fp32, converted during staging).
// OUTM: 0 = fp32 (+bias/relu), 1 = bf16 (+bias/relu), 2 = fp32 atomicAdd,
//       3 = transposed bf16 (writes C^T[N][M]).
// GATHER: A rows gathered via gidx (fp32 A only).
// BKN: B stored [K][N] fp32 (staging transpose).
template <bool ABF, bool BBF, int OUTM, bool RELU, bool GATHER = false, bool BKN = false>
__global__ __launch_bounds__(256) void k_mfma(
    const void* __restrict__ Av, long lda, long a_ss, long a_sb,
    const void* __restrict__ Bv, long ldb, long b_ss, long b_sb,
    void* __restrict__ Cv, long ldc, long c_ss, long c_sb,
    const float* __restrict__ bias, long bias_ss,
    const int* __restrict__ gidx,
    int M, int N, int K, int zb, int ksplit)
{
  __shared__ unsigned short As[128][40];  // 32 k + 8 pad
  __shared__ unsigned short Bs[128][40];
  const int tid = threadIdx.x;
  const int zi = blockIdx.z;
  const int bi = zi / ksplit;
  const int ks = zi - bi * ksplit;
  const int sIdx = bi / zb;
  const int bIdx = bi - sIdx * zb;
  const int row0 = blockIdx.y * 128;
  const int col0 = blockIdx.x * 128;
  const int Kc = ((K + ksplit * 32 - 1) / (ksplit * 32)) * 32;
  const int kbeg = ks * Kc;
  const int kend = min(K, kbeg + Kc);
  if (kbeg >= kend) return;

  const char* Ab = (const char*)Av + ((long)sIdx * a_ss + (long)bIdx * a_sb) * (ABF ? 2 : 4);
  const char* Bb = (const char*)Bv + ((long)sIdx * b_ss + (long)bIdx * b_sb) * (BBF ? 2 : 4);
  char* Cb = (char*)Cv + ((long)sIdx * c_ss + (long)bIdx * c_sb) * ((OUTM == 1 || OUTM == 3) ? 2 : 4);

  const int w = tid >> 6, l = tid & 63;
  const int wr = w >> 1, wc = w & 1;
  const int lr = l & 15, lg = l >> 4;

  f32x4 acc[4][4];
#pragma unroll
  for (int m = 0; m < 4; ++m)
#pragma unroll
    for (int n = 0; n < 4; ++n) acc[m][n] = f32x4{0.f, 0.f, 0.f, 0.f};

  const int sr = tid >> 1;          // staged row 0..127
  const int sk = (tid & 1) * 16;    // staged k base

  for (int kt = kbeg; kt < kend; kt += 32) {
    // ---- stage A tile [128 rows][32 k]
    {
      const int gr = row0 + sr;
      if (ABF) {
        const unsigned short* src = (const unsigned short*)(Ab + ((long)gr * lda + kt + sk) * 2);
        if (gr < M && kt + sk + 16 <= kend) {
          const uint2* p = (const uint2*)src;
          *(uint2*)&As[sr][sk + 0]  = p[0];
          *(uint2*)&As[sr][sk + 4]  = p[1];
          *(uint2*)&As[sr][sk + 8]  = p[2];
          *(uint2*)&As[sr][sk + 12] = p[3];
        } else {
#pragma unroll
          for (int i = 0; i < 16; ++i) {
            const int kk = kt + sk + i;
            As[sr][sk + i] = (gr < M && kk < kend) ? src[i] : (unsigned short)0;
          }
        }
      } else {
        const float* src;
        if (GATHER) src = (const float*)Av + ((gr < M) ? (long)gidx[gr] * lda : 0) + kt + sk;
        else        src = (const float*)(Ab + ((long)gr * lda + kt + sk) * 4);
        if (gr < M && kt + sk + 16 <= kend) {
#pragma unroll
          for (int q = 0; q < 4; ++q) {
            const float4 v = ((const float4*)src)[q];
            *(unsigned*)&As[sr][sk + q * 4 + 0] = (unsigned)f2bs(v.x) | ((unsigned)f2bs(v.y) << 16);
            *(unsigned*)&As[sr][sk + q * 4 + 2] = (unsigned)f2bs(v.z) | ((unsigned)f2bs(v.w) << 16);
          }
        } else {
#pragma unroll
          for (int i = 0; i < 16; ++i) {
            const int kk = kt + sk + i;
            As[sr][sk + i] = (gr < M && kk < kend) ? f2bs(src[i]) : (unsigned short)0;
          }
        }
      }
    }
    // ---- stage B tile [128 cols][32 k]
    if (BKN) {
      // B stored [K][N] fp32: transpose during staging
      const int kk = tid >> 3;          // k-local 0..31
      const int cb = (tid & 7) * 16;    // col base
      const int gk = kt + kk;
      const float* brow = (const float*)(Bb + (long)gk * ldb * 4);
#pragma unroll
      for (int q = 0; q < 4; ++q) {
        const int gc = col0 + cb + q * 4;
        float4 v = float4{0.f, 0.f, 0.f, 0.f};
        if (gk < kend) {
          if (gc + 4 <= N) v = *(const float4*)&brow[gc];
          else {
            if (gc + 0 < N) v.x = brow[gc + 0];
            if (gc + 1 < N) v.y = brow[gc + 1];
            if (gc + 2 < N) v.z = brow[gc + 2];
            if (gc + 3 < N) v.w = brow[gc + 3];
          }
        }
        Bs[cb + q * 4 + 0][kk] = f2bs(v.x);
        Bs[cb + q * 4 + 1][kk] = f2bs(v.y);
        Bs[cb + q * 4 + 2][kk] = f2bs(v.z);
        Bs[cb + q * 4 + 3][kk] = f2bs(v.w);
      }
    } else {
      const int gc = col0 + sr;
      if (BBF) {
        const unsigned short* src = (const unsigned short*)(Bb + ((long)gc * ldb + kt + sk) * 2);
        if (gc < N && kt + sk + 16 <= kend) {
          const uint2* p = (const uint2*)src;
          *(uint2*)&Bs[sr][sk + 0]  = p[0];
          *(uint2*)&Bs[sr][sk + 4]  = p[1];
          *(uint2*)&Bs[sr][sk + 8]  = p[2];
          *(uint2*)&Bs[sr][sk + 12] = p[3];
        } else {
#pragma unroll
          for (int i = 0; i < 16; ++i) {
            const int kk = kt + sk + i;
            Bs[sr][sk + i] = (gc < N && kk < kend) ? src[i] : (unsigned short)0;
          }
        }
      } else {
        const float* src = (const float*)(Bb + ((long)gc * ldb + kt + sk) * 4);
        if (gc < N && kt + sk + 16 <= kend) {
#pragma unroll
          for (int q = 0; q < 4; ++q) {
            const float4 v = ((const float4*)src)[q];
            *(unsigned*)&Bs[sr][sk + q * 4 + 0] = (unsigned)f2bs(v.x) | ((unsigned)f2bs(v.y) << 16);
            *(unsigned*)&Bs[sr][sk + q * 4 + 2] = (unsigned)f2bs(v.z) | ((unsigned)f2bs(v.w) << 16);
          }
        } else {
#pragma unroll
          for (int i = 0; i < 16; ++i) {
            const int kk = kt + sk + i;
            Bs[sr][sk + i] = (gc < N && kk < kend) ? f2bs(src[i]) : (unsigned short)0;
          }
        }
      }
    }
    __syncthreads();
    // ---- compute
    bf16x8 af[4], bf[4];
#pragma unroll
    for (int m = 0; m < 4; ++m)
      af[m] = *(const bf16x8*)&As[wr * 64 + m * 16 + lr][lg * 8];
#pragma unroll
    for (int n = 0; n < 4; ++n)
      bf[n] = *(const bf16x8*)&Bs[wc * 64 + n * 16 + lr][lg * 8];
#pragma unroll
    for (int m = 0; m < 4; ++m)
#pragma unroll
      for (int n = 0; n < 4; ++n)
        acc[m][n] = __builtin_amdgcn_mfma_f32_16x16x32_bf16(af[m], bf[n], acc[m][n], 0, 0, 0);
    __syncthreads();
  }

  // ---- epilogue
  const float* bp = bias ? bias + (long)sIdx * bias_ss : nullptr;
#pragma unroll
  for (int m = 0; m < 4; ++m) {
#pragma unroll
    for (int n = 0; n < 4; ++n) {
      const int col = col0 + wc * 64 + n * 16 + lr;
      const int rb  = row0 + wr * 64 + m * 16 + lg * 4;
      const f32x4 v = acc[m][n];
      if (col >= N) continue;
      if (OUTM == 3) {
        unsigned short* ct = (unsigned short*)Cb + (long)col * ldc + rb;
        if (rb + 4 <= M) {
          ushort4 pk;
          pk.x = f2bs(v[0]); pk.y = f2bs(v[1]); pk.z = f2bs(v[2]); pk.w = f2bs(v[3]);
          *(ushort4*)ct = pk;
        } else {
#pragma unroll
          for (int r = 0; r < 4; ++r) if (rb + r < M) ct[r] = f2bs(v[r]);
        }
      } else {
        const float bv = bp ? bp[col] : 0.f;
#pragma unroll
        for (int r = 0; r < 4; ++r) {
          const int row = rb + r;
          if (row >= M) continue;
          float x = v[r] + bv;
          if (RELU) x = fmaxf(x, 0.f);
          if (OUTM == 0) ((float*)Cb)[(long)row * ldc + col] = x;
          else if (OUTM == 1) ((unsigned short*)Cb)[(long)row * ldc + col] = f2bs(x);
          else atomicAdd((float*)Cb + (long)row * ldc + col, x);
        }
      }
    }
  }
}

// ---------------- MFMA GRU recurrence --------------------------------------
// One block = one chain-group of up to 16 chains sharing one weight matrix.
// 512 threads, 8 waves. whh [768][256] held register-resident as bf16 B-frags
// (wave w owns cols w*96..w*96+95; 48 frags = 192 VGPR). h state in thread
// registers; per step: 16x768x256 GEMM via MFMA + fused GRU activation.
__global__ __launch_bounds__(512, 1) void k_gru_mfma(
    const float* __restrict__ xg,             // [ctot][T][768] (incl. bih)
    const float* __restrict__ h0, int h0_mod, // null -> zeros
    const float* __restrict__ whh, long w_stride, int cpw,
    const float* __restrict__ bhh, long b_stride,
    float* __restrict__ ys, float* __restrict__ hT,
    int T, int ctot)
{
  const int g = blockIdx.x;
  const int tid = threadIdx.x;
  const int c0 = g * 16;
  const int nc = min(16, ctot - c0);
  const int widx = c0 / cpw;
  const float* W  = whh + (long)widx * w_stride;
  const float* Bh = bhh + (long)widx * b_stride;

  const int wv = tid >> 6;       // wave 0..7
  const int l  = tid & 63;
  const int lr = l & 15;
  const int lg = l >> 4;

  const int chain = tid & 15;
  const int jb    = tid >> 4;    // 0..31
  const int j0    = jb * 8;
  const int c     = c0 + chain;
  const bool vld  = chain < nc;

  __shared__ unsigned short A_lds[2][8][64][8];  // [buf][ktile][lane][elem]
  __shared__ float gate_lds[16][772];            // [chain][gatecol] (pad 4)
  __shared__ float bhh_lds[768];

  for (int i = tid; i < 768; i += 512) bhh_lds[i] = Bh[i];

  // ---- preload weight fragments (48 per wave, fully static indices)
  bf16x8 bfr[2][3][8];
#pragma unroll
  for (int p = 0; p < 2; ++p)
#pragma unroll
    for (int nt = 0; nt < 3; ++nt) {
      const int col = wv * 96 + (p * 3 + nt) * 16 + lr;
      const float* wp = W + (long)col * 256 + lg * 8;
#pragma unroll
      for (int kt = 0; kt < 8; ++kt) {
        const float4 v0 = *(const float4*)(wp + kt * 32);
        const float4 v1 = *(const float4*)(wp + kt * 32 + 4);
        bf16x8 pk;
        pk[0] = (short)f2bs(v0.x); pk[1] = (short)f2bs(v0.y);
        pk[2] = (short)f2bs(v0.z); pk[3] = (short)f2bs(v0.w);
        pk[4] = (short)f2bs(v1.x); pk[5] = (short)f2bs(v1.y);
        pk[6] = (short)f2bs(v1.z); pk[7] = (short)f2bs(v1.w);
        bfr[p][nt][kt] = pk;
      }
    }

  // ---- h init + initial A fill
  float h[8];
#pragma unroll
  for (int e = 0; e < 8; ++e)
    h[e] = (vld && h0) ? h0[(long)(c % h0_mod) * 256 + j0 + e] : 0.f;
  {
    bf16x8 pk;
#pragma unroll
    for (int e = 0; e < 8; ++e) pk[e] = (short)f2bs(h[e]);
    *(bf16x8*)&A_lds[0][jb >> 2][(jb & 3) * 16 + chain][0] = pk;
  }
  __syncthreads();

  const float* xrow = xg + (long)c * T * 768 + j0;
  float* yrow = ys ? ys + (long)c * T * 256 + j0 : nullptr;
  int cur = 0;

  for (int t = 0; t < T; ++t) {
    // issue this step's x-gate loads (consumed after the barrier)
    float xr[8], xz[8], xn_[8];
    if (vld) {
      const float* xp = xrow + (long)t * 768;
      *(float4*)&xr[0]  = *(const float4*)(xp);
      *(float4*)&xr[4]  = *(const float4*)(xp + 4);
      *(float4*)&xz[0]  = *(const float4*)(xp + 256);
      *(float4*)&xz[4]  = *(const float4*)(xp + 260);
      *(float4*)&xn_[0] = *(const float4*)(xp + 512);
      *(float4*)&xn_[4] = *(const float4*)(xp + 516);
    } else {
#pragma unroll
      for (int e = 0; e < 8; ++e) { xr[e] = 0.f; xz[e] = 0.f; xn_[e] = 0.f; }
    }

    // ---- MFMA phase: two passes of 3 n-tiles
#pragma unroll
    for (int p = 0; p < 2; ++p) {
      f32x4 acc[3];
#pragma unroll
      for (int nt = 0; nt < 3; ++nt) acc[nt] = f32x4{0.f, 0.f, 0.f, 0.f};
#pragma unroll
      for (int kt = 0; kt < 8; ++kt) {
        const bf16x8 af = *(const bf16x8*)&A_lds[cur][kt][l][0];
#pragma unroll
        for (int nt = 0; nt < 3; ++nt)
          acc[nt] = __builtin_amdgcn_mfma_f32_16x16x32_bf16(af, bfr[p][nt][kt], acc[nt], 0, 0, 0);
      }
#pragma unroll
      for (int nt = 0; nt < 3; ++nt) {
        const int col = wv * 96 + (p * 3 + nt) * 16 + lr;
#pragma unroll
        for (int r = 0; r < 4; ++r)
          gate_lds[lg * 4 + r][col] = acc[nt][r];
      }
    }
    __syncthreads();

    // ---- activation: thread (chain, jb) owns h[j0..j0+7]
    float gr[8], gz[8], gn[8], br[8], bz[8], bn[8];
    *(float4*)&gr[0] = *(const float4*)&gate_lds[chain][j0];
    *(float4*)&gr[4] = *(const float4*)&gate_lds[chain][j0 + 4];
    *(float4*)&gz[0] = *(const float4*)&gate_lds[chain][256 + j0];
    *(float4*)&gz[4] = *(const float4*)&gate_lds[chain][256 + j0 + 4];
    *(float4*)&gn[0] = *(const float4*)&gate_lds[chain][512 + j0];
    *(float4*)&gn[4] = *(const float4*)&gate_lds[chain][512 + j0 + 4];
    *(float4*)&br[0] = *(const float4*)&bhh_lds[j0];
    *(float4*)&br[4] = *(const float4*)&bhh_lds[j0 + 4];
    *(float4*)&bz[0] = *(const float4*)&bhh_lds[256 + j0];
    *(float4*)&bz[4] = *(const float4*)&bhh_lds[256 + j0 + 4];
    *(float4*)&bn[0] = *(const float4*)&bhh_lds[512 + j0];
    *(float4*)&bn[4] = *(const float4*)&bhh_lds[512 + j0 + 4];
#pragma unroll
    for (int e = 0; e < 8; ++e) {
      const float rr = sigf(xr[e] + gr[e] + br[e]);
      const float zz = sigf(xz[e] + gz[e] + bz[e]);
      const float nv = tanhf_(xn_[e] + rr * (gn[e] + bn[e]));
      h[e] = (1.f - zz) * nv + zz * h[e];
    }
    {
      bf16x8 pk;
#pragma unroll
      for (int e = 0; e < 8; ++e) pk[e] = (short)f2bs(h[e]);
      *(bf16x8*)&A_lds[cur ^ 1][jb >> 2][(jb & 3) * 16 + chain][0] = pk;
    }
    if (vld && yrow) {
      float* yp = yrow + (long)t * 256;
      *(float4*)yp = *(const float4*)&h[0];
      *(float4*)(yp + 4) = *(const float4*)&h[4];
    }
    __syncthreads();
    cur ^= 1;
  }
  if (hT && vld) {
    float* hp = hT + (long)c * 256 + j0;
    *(float4*)hp = *(const float4*)&h[0];
    *(float4*)(hp + 4) = *(const float4*)&h[4];
  }
}

// ---------------- C[M,N] = bias[N] ------------------------------------------
__global__ __launch_bounds__(256) void k_init_bias(
    float* __restrict__ C, const float* __restrict__ bias, int M, int N)
{
  const int total = M * N;
  for (int i = blockIdx.x * 256 + threadIdx.x; i < total; i += gridDim.x * 256)
    C[i] = bias[i % N];
}

// ---------------- astwork_bf[s][b][n][d] = bf16(emb_ast[x2[b][s][n]][d]) ----
__global__ __launch_bounds__(256) void k_gather_ast(
    const float* __restrict__ emb, const int* __restrict__ x2,
    unsigned short* __restrict__ outp)
{
  const int total = 4 * 32 * 300 * 300;
  for (int idx = blockIdx.x * 256 + threadIdx.x; idx < total; idx += gridDim.x * 256) {
    const int d = idx % 300;
    const int r = idx / 300;
    const int n = r % 300;
    const int r2 = r / 300;
    const int b = r2 % 32;
    const int s = r2 / 32;
    outp[idx] = f2bs(emb[(long)x2[(b * 4 + s) * 300 + n] * 300 + d]);
  }
}

// ---------------- oT[c][r] = bf16(w[r][c]) ----------------------------------
__global__ __launch_bounds__(256) void k_twb(
    const float* __restrict__ w, unsigned short* __restrict__ o, int R, int C)
{
  const int total = R * C;
  for (int i = blockIdx.x * 256 + threadIdx.x; i < total; i += gridDim.x * 256) {
    const int r = i / C, c = i - r * C;
    o[(long)c * R + r] = f2bs(w[i]);
  }
}

// ---------------- fp32 -> bf16 copy ----------------------------------------
__global__ __launch_bounds__(256) void k_f2b(
    const float* __restrict__ a, unsigned short* __restrict__ o, int n)
{
  for (int i = blockIdx.x * 256 + threadIdx.x; i < n; i += gridDim.x * 256)
    o[i] = f2bs(a[i]);
}

// ---------------- dot-product attention ------------------------------------
__global__ __launch_bounds__(256) void k_attn(
    const float* __restrict__ q, const float* __restrict__ kv,
    float* __restrict__ out, int Q, int L)
{
  const int bq = blockIdx.x;
  const int b = bq / Q;
  const int tid = threadIdx.x;
  const int g = tid >> 3, l = tid & 7;
  __shared__ float qv[256];
  __shared__ float sc[64];
  qv[tid] = q[(long)bq * 256 + tid];
  __syncthreads();
  for (int k0 = 0; k0 < L; k0 += 32) {
    const int k = k0 + g;
    float s = 0.f;
    if (k < L) {
      const float* kr = kv + ((long)b * L + k) * 256;
      for (int d = l; d < 256; d += 8) s += qv[d] * kr[d];
    }
    s += __shfl_xor(s, 1);
    s += __shfl_xor(s, 2);
    s += __shfl_xor(s, 4);
    if (k < L && l == 0) sc[k] = s * 0.0625f;
  }
  __syncthreads();
  float m = -1e30f;
  for (int k = 0; k < L; ++k) m = fmaxf(m, sc[k]);
  float den = 0.f;
  for (int k = 0; k < L; ++k) den += __expf(sc[k] - m);
  __syncthreads();
  if (tid < L) sc[tid] = __expf(sc[tid] - m);
  __syncthreads();
  const float* kb = kv + (long)b * L * 256;
  float acc = 0.f;
  for (int k = 0; k < L; ++k) acc += sc[k] * kb[(long)k * 256 + tid];
  out[(long)bq * 256 + tid] = acc / den;
}

// ---------------- hierarchy attention weights ------------------------------
__global__ __launch_bounds__(64) void k_hier(
    const float* __restrict__ dec, const float* __restrict__ g4out,
    float* __restrict__ ahier, int Q)
{
  const int bq = blockIdx.x;
  const int b = bq / Q;
  const int l = threadIdx.x;
  float s[4] = {0.f, 0.f, 0.f, 0.f};
#pragma unroll
  for (int i = 0; i < 4; ++i) {
    const int d = l * 4 + i;
    const float qd = dec[(long)bq * 256 + d];
#pragma unroll
    for (int sg = 0; sg < 4; ++sg)
      s[sg] += qd * g4out[((long)sg * 32 + b) * 256 + d];
  }
#pragma unroll
  for (int off = 32; off >= 1; off >>= 1)
#pragma unroll
    for (int sg = 0; sg < 4; ++sg) s[sg] += __shfl_xor(s[sg], off);
  if (l == 0) {
    float m = -1e30f;
#pragma unroll
    for (int sg = 0; sg < 4; ++sg) m = fmaxf(m, s[sg] * 0.0625f);
    float e[4], den = 0.f;
#pragma unroll
    for (int sg = 0; sg < 4; ++sg) { e[sg] = __expf(s[sg] * 0.0625f - m); den += e[sg]; }
#pragma unroll
    for (int sg = 0; sg < 4; ++sg) ahier[(long)bq * 4 + sg] = e[sg] / den;
  }
}

// ---------------- row softmax * hierarchy weight ---------------------------
__global__ __launch_bounds__(64) void k_smax(
    float* __restrict__ sc, const float* __restrict__ ahier)
{
  const int id = blockIdx.x;          // s*960 + (b*30+q)
  const int s = id / 960;
  const int bq = id - s * 960;
  float* row = sc + (long)id * 300;
  const int l = threadIdx.x;
  float v[5];
  float m = -1e30f;
#pragma unroll
  for (int i = 0; i < 5; ++i) {
    const int k = l + i * 64;
    v[i] = (k < 300) ? row[k] * 0.0625f : -1e30f;
    m = fmaxf(m, v[i]);
  }
#pragma unroll
  for (int off = 32; off >= 1; off >>= 1) m = fmaxf(m, __shfl_xor(m, off));
  float den = 0.f;
#pragma unroll
  for (int i = 0; i < 5; ++i) { v[i] = __expf(v[i] - m); den += v[i]; }
#pragma unroll
  for (int off = 32; off >= 1; off >>= 1) den += __shfl_xor(den, off);
  const float w = ahier[(long)bq * 4 + s] / den;
#pragma unroll
  for (int i = 0; i < 5; ++i) {
    const int k = l + i * 64;
    if (k < 300) row[k] = v[i] * w;
  }
}

// ---------------- concat [tctx | dec | actx] -> [960][768] ------------------
__global__ __launch_bounds__(256) void k_concat(
    const float* __restrict__ a, const float* __restrict__ b,
    const float* __restrict__ c, float* __restrict__ out, int rows)
{
  const int total = rows * 768;
  for (int i = blockIdx.x * 256 + threadIdx.x; i < total; i += gridDim.x * 256) {
    const int r = i / 768, col = i - r * 768;
    float v;
    if (col < 256) v = a[(long)r * 256 + col];
    else if (col < 512) v = b[(long)r * 256 + col - 256];
    else v = c[(long)r * 256 + col - 512];
    out[i] = v;
  }
}

// ---------------------------------------------------------------------------
extern "C" void kernel_launch(void* const* d_in, const int* in_sizes, int n_in,
                              void* d_out, int out_size, void* d_ws, size_t ws_size,
                              hipStream_t stream) {
  const int*   x0      = (const int*)d_in[0];
  const int*   x1      = (const int*)d_in[1];
  const int*   x2      = (const int*)d_in[2];
  const float* adj     = (const float*)d_in[3];
  const float* emb_ast = (const float*)d_in[4];
  const float* emb_com = (const float*)d_in[5];
  const float* g1_wih  = (const float*)d_in[6];
  const float* g1_whh  = (const float*)d_in[7];
  const float* g1_bih  = (const float*)d_in[8];
  const float* g1_bhh  = (const float*)d_in[9];
  const float* g2_wih  = (const float*)d_in[10];
  const float* g2_whh  = (const float*)d_in[11];
  const float* g2_bih  = (const float*)d_in[12];
  const float* g2_bhh  = (const float*)d_in[13];
  const float* g4_wih  = (const float*)d_in[14];
  const float* g4_whh  = (const float*)d_in[15];
  const float* g4_bih  = (const float*)d_in[16];
  const float* g4_bhh  = (const float*)d_in[17];
  const float* g58_wih = (const float*)d_in[18];
  const float* g58_whh = (const float*)d_in[19];
  const float* g58_bih = (const float*)d_in[20];
  const float* g58_bhh = (const float*)d_in[21];
  const float* gcn_w   = (const float*)d_in[22];
  const float* gcn_b   = (const float*)d_in[23];
  const float* dw      = (const float*)d_in[24];
  const float* db      = (const float*)d_in[25];
  const float* lw      = (const float*)d_in[26];
  const float* lb      = (const float*)d_in[27];
  float* out = (float*)d_out;
  float* ws  = (float*)d_ws;

  // workspace layout (float offsets; bf16 buffers use half the floats)
  unsigned short* astwork_bf = (unsigned short*)ws;               // [4][32][300][300] bf16
  unsigned short* supportT   = (unsigned short*)(ws + 5760000L);  // [4][32][300][300] bf16 (transposed)
  float* g58xg   = ws + 11520000L;  // [4][32][300][768]
  float* outsb   = ws + 41011200L;  // [4][32][300][256]
  float* xg1     = ws + 50841600L;  // [32][50][768]
  float* tenc    = ws + 52070400L;  // [32][50][256]
  float* tstate  = ws + 52480000L;  // [32][256]
  float* xg2     = ws + 52488192L;  // [32][30][768]
  float* dec     = ws + 53225472L;  // [32][30][256]
  float* tctx    = ws + 53471232L;  // [32][30][256]
  float* g4xg    = ws + 53716992L;  // [4][32][768]
  float* g4out   = ws + 53815296L;  // [4][32][256]
  float* ahier   = ws + 53848064L;  // [32][30][4]
  float* actx1   = ws + 53851904L;  // [32][30][256]
  float* actx    = ws + 54097664L;  // [32][30][256]
  float* dense   = ws + 54343424L;  // [32][30][256]
  float* ctmp    = ws + 54589184L;  // [960][768] concat
  float* scbuf   = ws + 55326464L;  // [4][32][30][300]
  unsigned short* gcn_wT   = (unsigned short*)(ws + 56478464L);   // [300][300] bf16
  unsigned short* dense_bf = (unsigned short*)(ws + 56523464L);   // [960][256] bf16

  const dim3 blk(256);

  // 1) gather astwork (bf16) + transpose gcn_w (bf16)
  k_gather_ast<<<dim3(4096), blk, 0, stream>>>(emb_ast, x2, astwork_bf);
  k_twb<<<dim3(90), blk, 0, stream>>>(gcn_w, gcn_wT, 300, 300);

  // 2) GCN, 2 hops (MFMA): supportT = (X @ W)^T ; X = relu(adj @ support + b)
  for (int hop = 0; hop < 2; ++hop) {
    k_mfma<true, true, 3, false><<<dim3(3, 3, 128), blk, 0, stream>>>(
        astwork_bf, 300, 2880000, 90000,
        gcn_wT, 300, 0, 0,
        supportT, 300, 2880000, 90000,
        nullptr, 0, nullptr, 300, 300, 300, 32, 1);
    k_mfma<false, true, 1, true><<<dim3(3, 3, 128), blk, 0, stream>>>(
        adj, 300, 90000, 360000,
        supportT, 300, 2880000, 90000,
        astwork_bf, 300, 2880000, 90000,
        gcn_b, 0, nullptr, 300, 300, 300, 32, 1);
  }

  // 3) token encoder GRU1: input gates (MFMA gather) + recurrence
  k_mfma<false, false, 0, false, true><<<dim3(6, 13, 1), blk, 0, stream>>>(
      emb_ast, 300, 0, 0, g1_wih, 300, 0, 0, xg1, 768, 0, 0,
      g1_bih, 0, x0, 1600, 768, 300, 1, 1);
  k_gru_mfma<<<dim3(2), dim3(512), 0, stream>>>(
      xg1, nullptr, 1, g1_whh, 0, 32, g1_bhh, 0, tenc, tstate, 50, 32);

  // 4) comment decoder GRU2
  k_mfma<false, false, 0, false, true><<<dim3(6, 8, 1), blk, 0, stream>>>(
      emb_com, 300, 0, 0, g2_wih, 300, 0, 0, xg2, 768, 0, 0,
      g2_bih, 0, x1, 960, 768, 300, 1, 1);
  k_gru_mfma<<<dim3(2), dim3(512), 0, stream>>>(
      xg2, tstate, 32, g2_whh, 0, 32, g2_bhh, 0, dec, nullptr, 30, 32);

  // 5) tcontext = dot_attn(dec, tenc)
  k_attn<<<dim3(960), blk, 0, stream>>>(dec, tenc, tctx, 30, 50);

  // 6) gru4: input gates via MFMA split-K atomic, then MFMA recurrence
  k_init_bias<<<dim3(384), blk, 0, stream>>>(g4xg, g4_bih, 128, 768);
  k_mfma<true, false, 2, false><<<dim3(6, 1, 43), blk, 0, stream>>>(
      astwork_bf, 90000, 0, 0, g4_wih, 90000, 0, 0, g4xg, 768, 0, 0,
      nullptr, 0, nullptr, 128, 768, 90000, 1, 43);
  k_gru_mfma<<<dim3(1), dim3(512), 0, stream>>>(
      g4xg, nullptr, 1, g4_whh, 0, 16, g4_bhh, 0, g4out, nullptr, 32, 4);

  // 7) hierarchy attention weights
  k_hier<<<dim3(960), dim3(64), 0, stream>>>(dec, g4out, ahier, 30);

  // 8) gru5..8 input gates (MFMA) + MFMA recurrence
  k_mfma<true, false, 0, false><<<dim3(6, 75, 4), blk, 0, stream>>>(
      astwork_bf, 300, 2880000, 0, g58_wih, 300, 230400, 0,
      g58xg, 768, 7372800, 0, g58_bih, 768, nullptr, 9600, 768, 300, 1, 1);
  k_gru_mfma<<<dim3(8), dim3(512), 0, stream>>>(
      g58xg, tstate, 32, g58_whh, 196608, 32, g58_bhh, 768, outsb, nullptr, 300, 128);

  // 9) node attention + hierarchical combine (all MFMA)
  k_mfma<false, false, 0, false><<<dim3(3, 1, 128), blk, 0, stream>>>(
      dec, 256, 0, 7680, outsb, 256, 2457600, 76800, scbuf, 300, 288000, 9000,
      nullptr, 0, nullptr, 30, 300, 256, 32, 1);
  k_smax<<<dim3(3840), dim3(64), 0, stream>>>(scbuf, ahier);
  hipMemsetAsync(actx1, 0, 245760 * sizeof(float), stream);
  k_mfma<false, false, 2, false, false, true><<<dim3(2, 1, 128), blk, 0, stream>>>(
      scbuf, 300, 288000, 9000, outsb, 256, 2457600, 76800, actx1, 256, 0, 7680,
      nullptr, 0, nullptr, 30, 256, 300, 32, 1);

  // 10) acontext = dot_attn(dec, actx1)
  k_attn<<<dim3(960), blk, 0, stream>>>(dec, actx1, actx, 30, 30);

  // 11) concat + dense (relu, MFMA) + bf16 copy
  k_concat<<<dim3(2880), blk, 0, stream>>>(tctx, dec, actx, ctmp, 960);
  k_mfma<false, false, 0, true><<<dim3(2, 8, 1), blk, 0, stream>>>(
      ctmp, 768, 0, 0, dw, 768, 0, 0, dense, 256, 0, 0,
      db, 0, nullptr, 960, 256, 768, 1, 1);
  k_f2b<<<dim3(960), blk, 0, stream>>>(dense, dense_bf, 245760);

  // 12) final linear via MFMA split-K (streams lw once)
  k_init_bias<<<dim3(1250), blk, 0, stream>>>(out, lb, 32, 10000);
  k_mfma<true, false, 2, false><<<dim3(79, 1, 6), blk, 0, stream>>>(
      dense_bf, 7680, 0, 0, lw, 7680, 0, 0, out, 10000, 0, 0,
      nullptr, 0, nullptr, 32, 10000, 7680, 1, 6);
}

// Round 5
// 1893.496 us; speedup vs baseline: 1.5375x; 1.5375x over previous
//
#include <hip/hip_runtime.h>
#include <hip/hip_fp16.h>
#include <hip/hip_bf16.h>

// ---------------------------------------------------------------------------
// HAConvGNN forward. Round 5: GRU recurrence = 1 block/chain, 1024 thr,
// 16 waves, weight register-resident (96 VGPR/thread bf16 frags), x-gates
// bf16 + LDS double-buffered prefetch. outsb/xg bf16 end-to-end.
// ---------------------------------------------------------------------------

typedef __attribute__((ext_vector_type(8))) short  bf16x8;
typedef __attribute__((ext_vector_type(4))) float  f32x4;

__device__ inline unsigned short f2bs(float f) {
  __hip_bfloat16 h = __float2bfloat16(f);
  unsigned short u; __builtin_memcpy(&u, &h, 2); return u;
}
__device__ inline float bs2f(unsigned short u) {
  unsigned v = (unsigned)u << 16;
  float f; __builtin_memcpy(&f, &v, 4); return f;
}
__device__ inline float sigf(float x) { return 1.f / (1.f + __expf(-x)); }
__device__ inline float tanhf_(float x) {
  const float e = __expf(-2.f * fabsf(x));
  return copysignf((1.f - e) / (1.f + e), x);
}

// ---------------- bf16 MFMA GEMM -------------------------------------------
// C[M,N] = A[M,K] * B^T (B stored [N][K]) with batching z=(batch, ksplit).
// ABF/BBF: operand is bf16 in global (else fp32, converted during staging).
// OUTM: 0 = fp32 (+bias/relu), 1 = bf16 (+bias/relu), 2 = fp32 atomicAdd,
//       3 = transposed bf16 (writes C^T[N][M]).
// GATHER: A rows gathered via gidx (fp32 A only).
// BKN: B stored [K][N] (staging transpose; dtype per BBF).
template <bool ABF, bool BBF, int OUTM, bool RELU, bool GATHER = false, bool BKN = false>
__global__ __launch_bounds__(256) void k_mfma(
    const void* __restrict__ Av, long lda, long a_ss, long a_sb,
    const void* __restrict__ Bv, long ldb, long b_ss, long b_sb,
    void* __restrict__ Cv, long ldc, long c_ss, long c_sb,
    const float* __restrict__ bias, long bias_ss,
    const int* __restrict__ gidx,
    int M, int N, int K, int zb, int ksplit)
{
  __shared__ unsigned short As[128][40];  // 32 k + 8 pad
  __shared__ unsigned short Bs[128][40];
  const int tid = threadIdx.x;
  const int zi = blockIdx.z;
  const int bi = zi / ksplit;
  const int ks = zi - bi * ksplit;
  const int sIdx = bi / zb;
  const int bIdx = bi - sIdx * zb;
  const int row0 = blockIdx.y * 128;
  const int col0 = blockIdx.x * 128;
  const int Kc = ((K + ksplit * 32 - 1) / (ksplit * 32)) * 32;
  const int kbeg = ks * Kc;
  const int kend = min(K, kbeg + Kc);
  if (kbeg >= kend) return;

  const char* Ab = (const char*)Av + ((long)sIdx * a_ss + (long)bIdx * a_sb) * (ABF ? 2 : 4);
  const char* Bb = (const char*)Bv + ((long)sIdx * b_ss + (long)bIdx * b_sb) * (BBF ? 2 : 4);
  char* Cb = (char*)Cv + ((long)sIdx * c_ss + (long)bIdx * c_sb) * ((OUTM == 1 || OUTM == 3) ? 2 : 4);

  const int w = tid >> 6, l = tid & 63;
  const int wr = w >> 1, wc = w & 1;
  const int lr = l & 15, lg = l >> 4;

  f32x4 acc[4][4];
#pragma unroll
  for (int m = 0; m < 4; ++m)
#pragma unroll
    for (int n = 0; n < 4; ++n) acc[m][n] = f32x4{0.f, 0.f, 0.f, 0.f};

  const int sr = tid >> 1;          // staged row 0..127
  const int sk = (tid & 1) * 16;    // staged k base

  for (int kt = kbeg; kt < kend; kt += 32) {
    // ---- stage A tile [128 rows][32 k]
    {
      const int gr = row0 + sr;
      if (ABF) {
        const unsigned short* src = (const unsigned short*)(Ab + ((long)gr * lda + kt + sk) * 2);
        if (gr < M && kt + sk + 16 <= kend) {
          const uint2* p = (const uint2*)src;
          *(uint2*)&As[sr][sk + 0]  = p[0];
          *(uint2*)&As[sr][sk + 4]  = p[1];
          *(uint2*)&As[sr][sk + 8]  = p[2];
          *(uint2*)&As[sr][sk + 12] = p[3];
        } else {
#pragma unroll
          for (int i = 0; i < 16; ++i) {
            const int kk = kt + sk + i;
            As[sr][sk + i] = (gr < M && kk < kend) ? src[i] : (unsigned short)0;
          }
        }
      } else {
        const float* src;
        if (GATHER) src = (const float*)Av + ((gr < M) ? (long)gidx[gr] * lda : 0) + kt + sk;
        else        src = (const float*)(Ab + ((long)gr * lda + kt + sk) * 4);
        if (gr < M && kt + sk + 16 <= kend) {
#pragma unroll
          for (int q = 0; q < 4; ++q) {
            const float4 v = ((const float4*)src)[q];
            *(unsigned*)&As[sr][sk + q * 4 + 0] = (unsigned)f2bs(v.x) | ((unsigned)f2bs(v.y) << 16);
            *(unsigned*)&As[sr][sk + q * 4 + 2] = (unsigned)f2bs(v.z) | ((unsigned)f2bs(v.w) << 16);
          }
        } else {
#pragma unroll
          for (int i = 0; i < 16; ++i) {
            const int kk = kt + sk + i;
            As[sr][sk + i] = (gr < M && kk < kend) ? f2bs(src[i]) : (unsigned short)0;
          }
        }
      }
    }
    // ---- stage B tile [128 cols][32 k]
    if (BKN) {
      // B stored [K][N]: transpose during staging (dtype per BBF)
      const int kk = tid >> 3;          // k-local 0..31
      const int cb = (tid & 7) * 16;    // col base
      const int gk = kt + kk;
#pragma unroll
      for (int q = 0; q < 16; ++q) {
        const int gc = col0 + cb + q;
        unsigned short v = 0;
        if (gk < kend && gc < N) {
          if (BBF) v = ((const unsigned short*)Bb)[(long)gk * ldb + gc];
          else     v = f2bs(((const float*)Bb)[(long)gk * ldb + gc]);
        }
        Bs[cb + q][kk] = v;
      }
    } else {
      const int gc = col0 + sr;
      if (BBF) {
        const unsigned short* src = (const unsigned short*)(Bb + ((long)gc * ldb + kt + sk) * 2);
        if (gc < N && kt + sk + 16 <= kend) {
          const uint2* p = (const uint2*)src;
          *(uint2*)&Bs[sr][sk + 0]  = p[0];
          *(uint2*)&Bs[sr][sk + 4]  = p[1];
          *(uint2*)&Bs[sr][sk + 8]  = p[2];
          *(uint2*)&Bs[sr][sk + 12] = p[3];
        } else {
#pragma unroll
          for (int i = 0; i < 16; ++i) {
            const int kk = kt + sk + i;
            Bs[sr][sk + i] = (gc < N && kk < kend) ? src[i] : (unsigned short)0;
          }
        }
      } else {
        const float* src = (const float*)(Bb + ((long)gc * ldb + kt + sk) * 4);
        if (gc < N && kt + sk + 16 <= kend) {
#pragma unroll
          for (int q = 0; q < 4; ++q) {
            const float4 v = ((const float4*)src)[q];
            *(unsigned*)&Bs[sr][sk + q * 4 + 0] = (unsigned)f2bs(v.x) | ((unsigned)f2bs(v.y) << 16);
            *(unsigned*)&Bs[sr][sk + q * 4 + 2] = (unsigned)f2bs(v.z) | ((unsigned)f2bs(v.w) << 16);
          }
        } else {
#pragma unroll
          for (int i = 0; i < 16; ++i) {
            const int kk = kt + sk + i;
            Bs[sr][sk + i] = (gc < N && kk < kend) ? f2bs(src[i]) : (unsigned short)0;
          }
        }
      }
    }
    __syncthreads();
    // ---- compute
    bf16x8 af[4], bf[4];
#pragma unroll
    for (int m = 0; m < 4; ++m)
      af[m] = *(const bf16x8*)&As[wr * 64 + m * 16 + lr][lg * 8];
#pragma unroll
    for (int n = 0; n < 4; ++n)
      bf[n] = *(const bf16x8*)&Bs[wc * 64 + n * 16 + lr][lg * 8];
#pragma unroll
    for (int m = 0; m < 4; ++m)
#pragma unroll
      for (int n = 0; n < 4; ++n)
        acc[m][n] = __builtin_amdgcn_mfma_f32_16x16x32_bf16(af[m], bf[n], acc[m][n], 0, 0, 0);
    __syncthreads();
  }

  // ---- epilogue
  const float* bp = bias ? bias + (long)sIdx * bias_ss : nullptr;
#pragma unroll
  for (int m = 0; m < 4; ++m) {
#pragma unroll
    for (int n = 0; n < 4; ++n) {
      const int col = col0 + wc * 64 + n * 16 + lr;
      const int rb  = row0 + wr * 64 + m * 16 + lg * 4;
      const f32x4 v = acc[m][n];
      if (col >= N) continue;
      if (OUTM == 3) {
        unsigned short* ct = (unsigned short*)Cb + (long)col * ldc + rb;
        if (rb + 4 <= M) {
          ushort4 pk;
          pk.x = f2bs(v[0]); pk.y = f2bs(v[1]); pk.z = f2bs(v[2]); pk.w = f2bs(v[3]);
          *(ushort4*)ct = pk;
        } else {
#pragma unroll
          for (int r = 0; r < 4; ++r) if (rb + r < M) ct[r] = f2bs(v[r]);
        }
      } else {
        const float bv = bp ? bp[col] : 0.f;
#pragma unroll
        for (int r = 0; r < 4; ++r) {
          const int row = rb + r;
          if (row >= M) continue;
          float x = v[r] + bv;
          if (RELU) x = fmaxf(x, 0.f);
          if (OUTM == 0) ((float*)Cb)[(long)row * ldc + col] = x;
          else if (OUTM == 1) ((unsigned short*)Cb)[(long)row * ldc + col] = f2bs(x);
          else atomicAdd((float*)Cb + (long)row * ldc + col, x);
        }
      }
    }
  }
}

// ---------------- MFMA GRU recurrence, 1 chain / block ----------------------
// 1024 threads = 16 waves. whh[768][256] bf16 register-resident: wave wv
// owns output cols wv*48..wv*48+47 (3 n-tiles x 8 k-tiles = 24 bf16x8 =
// 96 VGPR/thread). h state fp32 in LDS; per step: 16x256x768 MFMA (row 0
// real), gate transpose via LDS, 32-thread fused GRU activation.
// XBF: xg bf16 (else fp32). YBF: ys bf16 (else fp32).
template <bool XBF, bool YBF>
__global__ __launch_bounds__(1024, 1) void k_gru_v3(
    const void* __restrict__ xg,              // [chains][T][768] (incl bih)
    const float* __restrict__ h0, int h0_mod, // null -> zeros
    const unsigned short* __restrict__ whh_bf, long w_stride, int cpw,
    const float* __restrict__ bhh, long b_stride,
    void* __restrict__ ys, float* __restrict__ hT, int T)
{
  const int c   = blockIdx.x;
  const int tid = threadIdx.x;
  const int wv  = tid >> 6;
  const int l   = tid & 63;
  const int lr  = l & 15;
  const int lg  = l >> 4;

  __shared__ unsigned short A_lds[8][64][8];  // A fragments (row 0 = h)
  __shared__ float gate_lds[772];
  __shared__ float bhh_lds[768];
  __shared__ float h_lds[256];
  __shared__ uint4 xbuf[2][192];              // 3072 B per buffer

  // ---- weight fragments (B-operand): col = wv*48+nt*16+lr, k = kt*32+lg*8+e
  const unsigned short* W = whh_bf + (long)(c / cpw) * w_stride;
  bf16x8 bfr[3][8];
#pragma unroll
  for (int nt = 0; nt < 3; ++nt) {
    const unsigned short* wp = W + (long)(wv * 48 + nt * 16 + lr) * 256 + lg * 8;
#pragma unroll
    for (int kt = 0; kt < 8; ++kt)
      bfr[nt][kt] = *(const bf16x8*)(wp + kt * 32);
  }
  if (tid < 768) bhh_lds[tid] = bhh[(long)(c / cpw) * b_stride + tid];
  {
    unsigned* az = (unsigned*)A_lds;
    for (int i = tid; i < 2048; i += 1024) az[i] = 0;
  }
  __syncthreads();

  // ---- h0 + initial A fragment + stage x0
  if (tid < 32) {
    const int j0 = tid * 8;
    bf16x8 pk;
#pragma unroll
    for (int e = 0; e < 8; ++e) {
      const float hv = h0 ? h0[(long)(c % h0_mod) * 256 + j0 + e] : 0.f;
      h_lds[j0 + e] = hv;
      pk[e] = (short)f2bs(hv);
    }
    *(bf16x8*)&A_lds[j0 >> 5][((j0 >> 3) & 3) * 16][0] = pk;
  }
  const int esz = XBF ? 2 : 4;
  const int xlanes = XBF ? 96 : 192;
  const char* xbase = (const char*)xg + (long)c * T * 768 * esz;
  if (tid < xlanes) xbuf[0][tid] = *(const uint4*)(xbase + tid * 16);
  __syncthreads();

  int cur = 0;
  for (int t = 0; t < T; ++t) {
    // prefetch x(t+1) into regs (overlaps MFMA phase)
    uint4 xs = uint4{0, 0, 0, 0};
    const bool xact = (tid < xlanes) && (t + 1 < T);
    if (xact) xs = *(const uint4*)(xbase + (long)(t + 1) * 768 * esz + tid * 16);

    // ---- MFMA phase: gates[768] = h @ W^T
    f32x4 acc[3];
    acc[0] = f32x4{0.f, 0.f, 0.f, 0.f};
    acc[1] = f32x4{0.f, 0.f, 0.f, 0.f};
    acc[2] = f32x4{0.f, 0.f, 0.f, 0.f};
#pragma unroll
    for (int kt = 0; kt < 8; ++kt) {
      const bf16x8 af = *(const bf16x8*)&A_lds[kt][l][0];
#pragma unroll
      for (int nt = 0; nt < 3; ++nt)
        acc[nt] = __builtin_amdgcn_mfma_f32_16x16x32_bf16(af, bfr[nt][kt], acc[nt], 0, 0, 0);
    }
    if (lg == 0) {   // C row 0 lives in reg 0 of lg==0 lanes
#pragma unroll
      for (int nt = 0; nt < 3; ++nt)
        gate_lds[wv * 48 + nt * 16 + lr] = acc[nt][0];
    }
    __syncthreads();

    // write prefetched x(t+1)
    if (xact) xbuf[cur ^ 1][tid] = xs;

    // ---- activation (32 threads; thread owns units j0..j0+7)
    if (tid < 32) {
      const int j0 = tid * 8;
      float hn[8];
#pragma unroll
      for (int e = 0; e < 8; ++e) {
        const int u = j0 + e;
        float xr, xz, xn;
        if (XBF) {
          const unsigned short* xp = (const unsigned short*)&xbuf[cur][0];
          xr = bs2f(xp[u]); xz = bs2f(xp[256 + u]); xn = bs2f(xp[512 + u]);
        } else {
          const float* xp = (const float*)&xbuf[cur][0];
          xr = xp[u]; xz = xp[256 + u]; xn = xp[512 + u];
        }
        const float rr = sigf(xr + gate_lds[u] + bhh_lds[u]);
        const float zz = sigf(xz + gate_lds[256 + u] + bhh_lds[256 + u]);
        const float nv = tanhf_(xn + rr * (gate_lds[512 + u] + bhh_lds[512 + u]));
        hn[e] = (1.f - zz) * nv + zz * h_lds[u];
      }
      bf16x8 pk;
#pragma unroll
      for (int e = 0; e < 8; ++e) {
        h_lds[j0 + e] = hn[e];
        pk[e] = (short)f2bs(hn[e]);
      }
      *(bf16x8*)&A_lds[j0 >> 5][((j0 >> 3) & 3) * 16][0] = pk;
      if (ys) {
        if (YBF) {
          unsigned short* yp = (unsigned short*)ys + ((long)c * T + t) * 256 + j0;
          *(bf16x8*)yp = pk;
        } else {
          float* yp = (float*)ys + ((long)c * T + t) * 256 + j0;
          *(float4*)yp = float4{hn[0], hn[1], hn[2], hn[3]};
          *(float4*)(yp + 4) = float4{hn[4], hn[5], hn[6], hn[7]};
        }
      }
    }
    __syncthreads();
    cur ^= 1;
  }
  if (hT && tid < 32) {
    const int j0 = tid * 8;
    float* hp = hT + (long)c * 256 + j0;
#pragma unroll
    for (int e = 0; e < 8; ++e) hp[e] = h_lds[j0 + e];
  }
}

// ---------------- C[M,N] = bias[N] ------------------------------------------
__global__ __launch_bounds__(256) void k_init_bias(
    float* __restrict__ C, const float* __restrict__ bias, int M, int N)
{
  const int total = M * N;
  for (int i = blockIdx.x * 256 + threadIdx.x; i < total; i += gridDim.x * 256)
    C[i] = bias[i % N];
}

// ---------------- astwork_bf[s][b][n][d] = bf16(emb_ast[x2[b][s][n]][d]) ----
__global__ __launch_bounds__(256) void k_gather_ast(
    const float* __restrict__ emb, const int* __restrict__ x2,
    unsigned short* __restrict__ outp)
{
  const int total = 4 * 32 * 300 * 300;
  for (int idx = blockIdx.x * 256 + threadIdx.x; idx < total; idx += gridDim.x * 256) {
    const int d = idx % 300;
    const int r = idx / 300;
    const int n = r % 300;
    const int r2 = r / 300;
    const int b = r2 % 32;
    const int s = r2 / 32;
    outp[idx] = f2bs(emb[(long)x2[(b * 4 + s) * 300 + n] * 300 + d]);
  }
}

// ---------------- oT[c][r] = bf16(w[r][c]) ----------------------------------
__global__ __launch_bounds__(256) void k_twb(
    const float* __restrict__ w, unsigned short* __restrict__ o, int R, int C)
{
  const int total = R * C;
  for (int i = blockIdx.x * 256 + threadIdx.x; i < total; i += gridDim.x * 256) {
    const int r = i / C, c = i - r * C;
    o[(long)c * R + r] = f2bs(w[i]);
  }
}

// ---------------- fp32 -> bf16 copy ----------------------------------------
__global__ __launch_bounds__(256) void k_f2b(
    const float* __restrict__ a, unsigned short* __restrict__ o, int n)
{
  for (int i = blockIdx.x * 256 + threadIdx.x; i < n; i += gridDim.x * 256)
    o[i] = f2bs(a[i]);
}

// ---------------- dot-product attention ------------------------------------
__global__ __launch_bounds__(256) void k_attn(
    const float* __restrict__ q, const float* __restrict__ kv,
    float* __restrict__ out, int Q, int L)
{
  const int bq = blockIdx.x;
  const int b = bq / Q;
  const int tid = threadIdx.x;
  const int g = tid >> 3, l = tid & 7;
  __shared__ float qv[256];
  __shared__ float sc[64];
  qv[tid] = q[(long)bq * 256 + tid];
  __syncthreads();
  for (int k0 = 0; k0 < L; k0 += 32) {
    const int k = k0 + g;
    float s = 0.f;
    if (k < L) {
      const float* kr = kv + ((long)b * L + k) * 256;
      for (int d = l; d < 256; d += 8) s += qv[d] * kr[d];
    }
    s += __shfl_xor(s, 1);
    s += __shfl_xor(s, 2);
    s += __shfl_xor(s, 4);
    if (k < L && l == 0) sc[k] = s * 0.0625f;
  }
  __syncthreads();
  float m = -1e30f;
  for (int k = 0; k < L; ++k) m = fmaxf(m, sc[k]);
  float den = 0.f;
  for (int k = 0; k < L; ++k) den += __expf(sc[k] - m);
  __syncthreads();
  if (tid < L) sc[tid] = __expf(sc[tid] - m);
  __syncthreads();
  const float* kb = kv + (long)b * L * 256;
  float acc = 0.f;
  for (int k = 0; k < L; ++k) acc += sc[k] * kb[(long)k * 256 + tid];
  out[(long)bq * 256 + tid] = acc / den;
}

// ---------------- hierarchy attention weights ------------------------------
__global__ __launch_bounds__(64) void k_hier(
    const float* __restrict__ dec, const float* __restrict__ g4out,
    float* __restrict__ ahier, int Q)
{
  const int bq = blockIdx.x;
  const int b = bq / Q;
  const int l = threadIdx.x;
  float s[4] = {0.f, 0.f, 0.f, 0.f};
#pragma unroll
  for (int i = 0; i < 4; ++i) {
    const int d = l * 4 + i;
    const float qd = dec[(long)bq * 256 + d];
#pragma unroll
    for (int sg = 0; sg < 4; ++sg)
      s[sg] += qd * g4out[((long)sg * 32 + b) * 256 + d];
  }
#pragma unroll
  for (int off = 32; off >= 1; off >>= 1)
#pragma unroll
    for (int sg = 0; sg < 4; ++sg) s[sg] += __shfl_xor(s[sg], off);
  if (l == 0) {
    float m = -1e30f;
#pragma unroll
    for (int sg = 0; sg < 4; ++sg) m = fmaxf(m, s[sg] * 0.0625f);
    float e[4], den = 0.f;
#pragma unroll
    for (int sg = 0; sg < 4; ++sg) { e[sg] = __expf(s[sg] * 0.0625f - m); den += e[sg]; }
#pragma unroll
    for (int sg = 0; sg < 4; ++sg) ahier[(long)bq * 4 + sg] = e[sg] / den;
  }
}

// ---------------- row softmax * hierarchy weight ---------------------------
__global__ __launch_bounds__(64) void k_smax(
    float* __restrict__ sc, const float* __restrict__ ahier)
{
  const int id = blockIdx.x;          // s*960 + (b*30+q)
  const int s = id / 960;
  const int bq = id - s * 960;
  float* row = sc + (long)id * 300;
  const int l = threadIdx.x;
  float v[5];
  float m = -1e30f;
#pragma unroll
  for (int i = 0; i < 5; ++i) {
    const int k = l + i * 64;
    v[i] = (k < 300) ? row[k] * 0.0625f : -1e30f;
    m = fmaxf(m, v[i]);
  }
#pragma unroll
  for (int off = 32; off >= 1; off >>= 1) m = fmaxf(m, __shfl_xor(m, off));
  float den = 0.f;
#pragma unroll
  for (int i = 0; i < 5; ++i) { v[i] = __expf(v[i] - m); den += v[i]; }
#pragma unroll
  for (int off = 32; off >= 1; off >>= 1) den += __shfl_xor(den, off);
  const float w = ahier[(long)bq * 4 + s] / den;
#pragma unroll
  for (int i = 0; i < 5; ++i) {
    const int k = l + i * 64;
    if (k < 300) row[k] = v[i] * w;
  }
}

// ---------------- concat [tctx | dec | actx] -> [960][768] ------------------
__global__ __launch_bounds__(256) void k_concat(
    const float* __restrict__ a, const float* __restrict__ b,
    const float* __restrict__ c, float* __restrict__ out, int rows)
{
  const int total = rows * 768;
  for (int i = blockIdx.x * 256 + threadIdx.x; i < total; i += gridDim.x * 256) {
    const int r = i / 768, col = i - r * 768;
    float v;
    if (col < 256) v = a[(long)r * 256 + col];
    else if (col < 512) v = b[(long)r * 256 + col - 256];
    else v = c[(long)r * 256 + col - 512];
    out[i] = v;
  }
}

// ---------------------------------------------------------------------------
extern "C" void kernel_launch(void* const* d_in, const int* in_sizes, int n_in,
                              void* d_out, int out_size, void* d_ws, size_t ws_size,
                              hipStream_t stream) {
  const int*   x0      = (const int*)d_in[0];
  const int*   x1      = (const int*)d_in[1];
  const int*   x2      = (const int*)d_in[2];
  const float* adj     = (const float*)d_in[3];
  const float* emb_ast = (const float*)d_in[4];
  const float* emb_com = (const float*)d_in[5];
  const float* g1_wih  = (const float*)d_in[6];
  const float* g1_whh  = (const float*)d_in[7];
  const float* g1_bih  = (const float*)d_in[8];
  const float* g1_bhh  = (const float*)d_in[9];
  const float* g2_wih  = (const float*)d_in[10];
  const float* g2_whh  = (const float*)d_in[11];
  const float* g2_bih  = (const float*)d_in[12];
  const float* g2_bhh  = (const float*)d_in[13];
  const float* g4_wih  = (const float*)d_in[14];
  const float* g4_whh  = (const float*)d_in[15];
  const float* g4_bih  = (const float*)d_in[16];
  const float* g4_bhh  = (const float*)d_in[17];
  const float* g58_wih = (const float*)d_in[18];
  const float* g58_whh = (const float*)d_in[19];
  const float* g58_bih = (const float*)d_in[20];
  const float* g58_bhh = (const float*)d_in[21];
  const float* gcn_w   = (const float*)d_in[22];
  const float* gcn_b   = (const float*)d_in[23];
  const float* dw      = (const float*)d_in[24];
  const float* db      = (const float*)d_in[25];
  const float* lw      = (const float*)d_in[26];
  const float* lb      = (const float*)d_in[27];
  float* out = (float*)d_out;
  float* ws  = (float*)d_ws;

  // workspace layout (float offsets; us = bf16 elements)
  unsigned short* astwork_bf = (unsigned short*)ws;                 // [4][32][300][300]
  unsigned short* supportT   = (unsigned short*)(ws + 5760000L);    // [4][32][300][300] transposed
  unsigned short* g58xg_bf   = (unsigned short*)(ws + 11520000L);   // [4][32][300][768]
  unsigned short* outsb_bf   = (unsigned short*)(ws + 26265600L);   // [4][32][300][256]
  unsigned short* xg1_bf     = (unsigned short*)(ws + 31180800L);   // [32][50][768]
  unsigned short* xg2_bf     = (unsigned short*)(ws + 31795200L);   // [32][30][768]
  float* tenc    = ws + 32163840L;  // [32][50][256]
  float* tstate  = ws + 32573440L;  // [32][256]
  float* dec     = ws + 32581632L;  // [32][30][256]
  float* tctx    = ws + 32827392L;  // [32][30][256]
  float* g4xg    = ws + 33073152L;  // [4][32][768] fp32 (atomic)
  float* g4out   = ws + 33171456L;  // [4][32][256]
  float* ahier   = ws + 33204224L;  // [32][30][4]
  float* actx1   = ws + 33208064L;  // [32][30][256]
  float* actx    = ws + 33453824L;  // [32][30][256]
  float* dense   = ws + 33699584L;  // [32][30][256]
  float* ctmp    = ws + 33945344L;  // [960][768]
  float* scbuf   = ws + 34682624L;  // [4][32][30][300]
  unsigned short* gcn_wT    = (unsigned short*)(ws + 35834624L);    // [300][300]
  unsigned short* dense_bf  = (unsigned short*)(ws + 35879624L);    // [960][256]
  unsigned short* g1whh_bf  = (unsigned short*)(ws + 36002504L);    // [768][256]
  unsigned short* g2whh_bf  = (unsigned short*)(ws + 36100808L);
  unsigned short* g4whh_bf  = (unsigned short*)(ws + 36199112L);
  unsigned short* g58whh_bf = (unsigned short*)(ws + 36297416L);    // [4][768][256]

  const dim3 blk(256);

  // 0) weight preps
  k_gather_ast<<<dim3(4096), blk, 0, stream>>>(emb_ast, x2, astwork_bf);
  k_twb<<<dim3(90), blk, 0, stream>>>(gcn_w, gcn_wT, 300, 300);
  k_f2b<<<dim3(192), blk, 0, stream>>>(g1_whh, g1whh_bf, 196608);
  k_f2b<<<dim3(192), blk, 0, stream>>>(g2_whh, g2whh_bf, 196608);
  k_f2b<<<dim3(192), blk, 0, stream>>>(g4_whh, g4whh_bf, 196608);
  k_f2b<<<dim3(768), blk, 0, stream>>>(g58_whh, g58whh_bf, 786432);

  // 2) GCN, 2 hops (MFMA): supportT = (X @ W)^T ; X = relu(adj @ support + b)
  for (int hop = 0; hop < 2; ++hop) {
    k_mfma<true, true, 3, false><<<dim3(3, 3, 128), blk, 0, stream>>>(
        astwork_bf, 300, 2880000, 90000,
        gcn_wT, 300, 0, 0,
        supportT, 300, 2880000, 90000,
        nullptr, 0, nullptr, 300, 300, 300, 32, 1);
    k_mfma<false, true, 1, true><<<dim3(3, 3, 128), blk, 0, stream>>>(
        adj, 300, 90000, 360000,
        supportT, 300, 2880000, 90000,
        astwork_bf, 300, 2880000, 90000,
        gcn_b, 0, nullptr, 300, 300, 300, 32, 1);
  }

  // 3) token encoder GRU1 (bf16 x-gates) + recurrence
  k_mfma<false, false, 1, false, true><<<dim3(6, 13, 1), blk, 0, stream>>>(
      emb_ast, 300, 0, 0, g1_wih, 300, 0, 0, xg1_bf, 768, 0, 0,
      g1_bih, 0, x0, 1600, 768, 300, 1, 1);
  k_gru_v3<true, false><<<dim3(32), dim3(1024), 0, stream>>>(
      xg1_bf, nullptr, 1, g1whh_bf, 0, 32, g1_bhh, 0, tenc, tstate, 50);

  // 4) comment decoder GRU2
  k_mfma<false, false, 1, false, true><<<dim3(6, 8, 1), blk, 0, stream>>>(
      emb_com, 300, 0, 0, g2_wih, 300, 0, 0, xg2_bf, 768, 0, 0,
      g2_bih, 0, x1, 960, 768, 300, 1, 1);
  k_gru_v3<true, false><<<dim3(32), dim3(1024), 0, stream>>>(
      xg2_bf, tstate, 32, g2whh_bf, 0, 32, g2_bhh, 0, dec, nullptr, 30);

  // 5) tcontext = dot_attn(dec, tenc)
  k_attn<<<dim3(960), blk, 0, stream>>>(dec, tenc, tctx, 30, 50);

  // 6) gru4: input gates via MFMA split-K atomic (fp32), then recurrence
  k_init_bias<<<dim3(384), blk, 0, stream>>>(g4xg, g4_bih, 128, 768);
  k_mfma<true, false, 2, false><<<dim3(6, 1, 43), blk, 0, stream>>>(
      astwork_bf, 90000, 0, 0, g4_wih, 90000, 0, 0, g4xg, 768, 0, 0,
      nullptr, 0, nullptr, 128, 768, 90000, 1, 43);
  k_gru_v3<false, false><<<dim3(4), dim3(1024), 0, stream>>>(
      g4xg, nullptr, 1, g4whh_bf, 0, 4, g4_bhh, 0, g4out, nullptr, 32);

  // 7) hierarchy attention weights
  k_hier<<<dim3(960), dim3(64), 0, stream>>>(dec, g4out, ahier, 30);

  // 8) gru5..8 input gates (MFMA, bf16 out) + recurrence (ys bf16)
  k_mfma<true, false, 1, false><<<dim3(6, 75, 4), blk, 0, stream>>>(
      astwork_bf, 300, 2880000, 0, g58_wih, 300, 230400, 0,
      g58xg_bf, 768, 7372800, 0, g58_bih, 768, nullptr, 9600, 768, 300, 1, 1);
  k_gru_v3<true, true><<<dim3(128), dim3(1024), 0, stream>>>(
      g58xg_bf, tstate, 32, g58whh_bf, 196608, 32, g58_bhh, 768,
      outsb_bf, nullptr, 300);

  // 9) node attention + hierarchical combine (bf16 V)
  k_mfma<false, true, 0, false><<<dim3(3, 1, 128), blk, 0, stream>>>(
      dec, 256, 0, 7680, outsb_bf, 256, 2457600, 76800, scbuf, 300, 288000, 9000,
      nullptr, 0, nullptr, 30, 300, 256, 32, 1);
  k_smax<<<dim3(3840), dim3(64), 0, stream>>>(scbuf, ahier);
  hipMemsetAsync(actx1, 0, 245760 * sizeof(float), stream);
  k_mfma<false, true, 2, false, false, true><<<dim3(2, 1, 128), blk, 0, stream>>>(
      scbuf, 300, 288000, 9000, outsb_bf, 256, 2457600, 76800, actx1, 256, 0, 7680,
      nullptr, 0, nullptr, 30, 256, 300, 32, 1);

  // 10) acontext = dot_attn(dec, actx1)
  k_attn<<<dim3(960), blk, 0, stream>>>(dec, actx1, actx, 30, 30);

  // 11) concat + dense (relu, MFMA) + bf16 copy
  k_concat<<<dim3(2880), blk, 0, stream>>>(tctx, dec, actx, ctmp, 960);
  k_mfma<false, false, 0, true><<<dim3(2, 8, 1), blk, 0, stream>>>(
      ctmp, 768, 0, 0, dw, 768, 0, 0, dense, 256, 0, 0,
      db, 0, nullptr, 960, 256, 768, 1, 1);
  k_f2b<<<dim3(960), blk, 0, stream>>>(dense, dense_bf, 245760);

  // 12) final linear via MFMA split-K (streams lw once)
  k_init_bias<<<dim3(1250), blk, 0, stream>>>(out, lb, 32, 10000);
  k_mfma<true, false, 2, false><<<dim3(79, 1, 6), blk, 0, stream>>>(
      dense_bf, 7680, 0, 0, lw, 7680, 0, 0, out, 10000, 0, 0,
      nullptr, 0, nullptr, 32, 10000, 7680, 1, 6);
}